// Round 6
// baseline (440.399 us; speedup 1.0000x reference)
//
#include <hip/hip_runtime.h>
#include <hip/hip_bf16.h>

#define N_NODES 50000
#define E_EDGES 800000
#define ETOT (E_EDGES + N_NODES)   // self-loops appended
#define IN_DIM 128
#define HID 64
#define HEADS 4
#define HC (HEADS * HID)           // 256
#define OUT_DIM 64
#define NEG_SLOPE 0.2f
#define SCAN_BLK 1024

using bf16x8 = __attribute__((ext_vector_type(8))) __bf16;
using f32x4  = __attribute__((ext_vector_type(4))) float;

// ---------------- fp32 -> bf16 convert (x) ----------------
__global__ __launch_bounds__(256) void cvt_bf16(const float* __restrict__ in,
                                                __hip_bfloat16* __restrict__ out,
                                                long n4) {   // n4 = n/4
    long i = (long)blockIdx.x * 256 + threadIdx.x;
    if (i >= n4) return;
    float4 v = ((const float4*)in)[i];
    __hip_bfloat162 a, b;
    a.x = __float2bfloat16(v.x); a.y = __float2bfloat16(v.y);
    b.x = __float2bfloat16(v.z); b.y = __float2bfloat16(v.w);
    ((__hip_bfloat162*)out)[2 * i]     = a;
    ((__hip_bfloat162*)out)[2 * i + 1] = b;
}

// ---------------- weight: W[K][N] fp32 -> Wt[N][K] bf16 ----------------
__global__ __launch_bounds__(256) void wtrans(const float* __restrict__ W,
                                              __hip_bfloat16* __restrict__ Wt,
                                              int K, int N) {
    int i = blockIdx.x * 256 + threadIdx.x;
    if (i >= K * N) return;
    int k = i / N, n = i - k * N;
    Wt[(long)n * K + k] = __float2bfloat16(W[i]);
}

// ---------------- MFMA GEMM + fused alphas ----------------
// C[M][256] = A[M][K](bf16) @ B[K][256](bf16, given transposed Bt[256][K]).
// Block: 256 thr = 4 waves; BM=64; wave h owns head h's 64 cols.
// Epilogue: bf16 C store + exact fp32 alpha dots (as_/ad_).
template <int K>
__global__ __launch_bounds__(256) void gemm_xh_mfma(const __hip_bfloat16* __restrict__ A,
                                                    const __hip_bfloat16* __restrict__ Bt,
                                                    __hip_bfloat16* __restrict__ Cb,
                                                    int M,
                                                    const float* __restrict__ a_src,
                                                    const float* __restrict__ a_dst,
                                                    float* __restrict__ as_,
                                                    float* __restrict__ ad_) {
    __shared__ unsigned short Atile[64][K + 8];
    const int t = threadIdx.x;
    const int h = t >> 6;          // wave = head
    const int lane = t & 63;
    const int l15 = lane & 15, l4 = lane >> 4;
    const int m0 = blockIdx.x * 64;

    // ---- stage A tile (64 x K bf16) ----
    constexpr int KB8 = K / 8;     // 16B chunks per row
#pragma unroll
    for (int i = 0; i < K / 32; i++) {        // 64*K/8/256 = K/32 chunks/thread
        int q = i * 256 + t;
        int row = q / KB8;
        int kc = (q - row * KB8) * 8;
        int gm = m0 + row;
        uint4 v = make_uint4(0, 0, 0, 0);
        if (gm < M) v = *(const uint4*)(A + (long)gm * K + kc);
        *(uint4*)&Atile[row][kc] = v;
    }
    __syncthreads();

    f32x4 acc[4][4];               // [rb][cb]
#pragma unroll
    for (int i = 0; i < 4; i++)
#pragma unroll
        for (int j = 0; j < 4; j++) acc[i][j] = (f32x4)0.f;

    const __hip_bfloat16* Bp = Bt + ((long)(h * 64 + l15)) * K + l4 * 8;

#pragma unroll
    for (int kb = 0; kb < K / 32; kb++) {
        bf16x8 bfr[4];
#pragma unroll
        for (int cb = 0; cb < 4; cb++)
            bfr[cb] = *(const bf16x8*)(Bp + (long)cb * 16 * K + kb * 32);
        bf16x8 afr[4];
#pragma unroll
        for (int rb = 0; rb < 4; rb++)
            afr[rb] = *(const bf16x8*)&Atile[rb * 16 + l15][kb * 32 + l4 * 8];
#pragma unroll
        for (int rb = 0; rb < 4; rb++)
#pragma unroll
            for (int cb = 0; cb < 4; cb++)
                acc[rb][cb] = __builtin_amdgcn_mfma_f32_16x16x32_bf16(afr[rb], bfr[cb], acc[rb][cb], 0, 0, 0);
    }

    // ---- epilogue ----
    float asv[4], adv[4];
#pragma unroll
    for (int cb = 0; cb < 4; cb++) {
        asv[cb] = a_src[h * HID + cb * 16 + l15];
        adv[cb] = a_dst[h * HID + cb * 16 + l15];
    }
#pragma unroll
    for (int rb = 0; rb < 4; rb++) {
#pragma unroll
        for (int reg = 0; reg < 4; reg++) {
            int row = m0 + rb * 16 + l4 * 4 + reg;
            float ps = 0.f, pd = 0.f;
#pragma unroll
            for (int cb = 0; cb < 4; cb++) {
                ps += acc[rb][cb][reg] * asv[cb];
                pd += acc[rb][cb][reg] * adv[cb];
            }
#pragma unroll
            for (int off = 8; off; off >>= 1) {
                ps += __shfl_down(ps, off);
                pd += __shfl_down(pd, off);
            }
            if (l15 == 0 && row < M) {
                as_[row * HEADS + h] = ps;
                ad_[row * HEADS + h] = pd;
            }
        }
    }
#pragma unroll
    for (int rb = 0; rb < 4; rb++) {
#pragma unroll
        for (int cb = 0; cb < 4; cb++) {
#pragma unroll
            for (int reg = 0; reg < 4; reg++) {
                int row = m0 + rb * 16 + l4 * 4 + reg;
                int col = h * 64 + cb * 16 + l15;
                if (row < M) Cb[(long)row * HC + col] = __float2bfloat16(acc[rb][cb][reg]);
            }
        }
    }
}

// ---------------- MFMA FC: out[M][64] = A[M][256](bf16) @ Wfct + bias ----------------
__global__ __launch_bounds__(256) void gemm_fc_mfma(const __hip_bfloat16* __restrict__ A,
                                                    const __hip_bfloat16* __restrict__ Bt,  // [64][256]
                                                    const float* __restrict__ bias,
                                                    float* __restrict__ C,
                                                    int M) {
    constexpr int K = 256;
    __shared__ unsigned short Atile[64][K + 8];
    const int t = threadIdx.x;
    const int w = t >> 6;
    const int lane = t & 63;
    const int l15 = lane & 15, l4 = lane >> 4;
    const int m0 = blockIdx.x * 64;

    constexpr int KB8 = K / 8;
#pragma unroll
    for (int i = 0; i < K / 32; i++) {
        int q = i * 256 + t;
        int row = q / KB8;
        int kc = (q - row * KB8) * 8;
        int gm = m0 + row;
        uint4 v = make_uint4(0, 0, 0, 0);
        if (gm < M) v = *(const uint4*)(A + (long)gm * K + kc);
        *(uint4*)&Atile[row][kc] = v;
    }
    __syncthreads();

    f32x4 acc[4];   // [cb], rows w*16..w*16+15
#pragma unroll
    for (int j = 0; j < 4; j++) acc[j] = (f32x4)0.f;

    const __hip_bfloat16* Bp = Bt + (long)l15 * K + l4 * 8;
#pragma unroll
    for (int kb = 0; kb < K / 32; kb++) {
        bf16x8 afr = *(const bf16x8*)&Atile[w * 16 + l15][kb * 32 + l4 * 8];
#pragma unroll
        for (int cb = 0; cb < 4; cb++) {
            bf16x8 bfr = *(const bf16x8*)(Bp + (long)cb * 16 * K + kb * 32);
            acc[cb] = __builtin_amdgcn_mfma_f32_16x16x32_bf16(afr, bfr, acc[cb], 0, 0, 0);
        }
    }
#pragma unroll
    for (int cb = 0; cb < 4; cb++) {
#pragma unroll
        for (int reg = 0; reg < 4; reg++) {
            int row = m0 + w * 16 + l4 * 4 + reg;
            int col = cb * 16 + l15;
            if (row < M) C[(long)row * OUT_DIM + col] = acc[cb][reg] + bias[col];
        }
    }
}

// ---------------- CSR build ----------------
__global__ __launch_bounds__(256) void hist_kernel(const int* __restrict__ ei,
                                                   int* __restrict__ deg) {
    int e = blockIdx.x * 256 + threadIdx.x;
    if (e >= ETOT) return;
    int d = (e < E_EDGES) ? ei[E_EDGES + e] : e - E_EDGES;
    atomicAdd(&deg[d], 1);
}

__global__ __launch_bounds__(SCAN_BLK) void scan_phase1(const int* __restrict__ deg,
                                                        int* __restrict__ rs,
                                                        int* __restrict__ partials,
                                                        int n) {
    __shared__ int tmp[SCAN_BLK];
    int i = blockIdx.x * SCAN_BLK + threadIdx.x;
    int v = (i < n) ? deg[i] : 0;
    tmp[threadIdx.x] = v;
    __syncthreads();
    for (int off = 1; off < SCAN_BLK; off <<= 1) {
        int t = (threadIdx.x >= (unsigned)off) ? tmp[threadIdx.x - off] : 0;
        __syncthreads();
        tmp[threadIdx.x] += t;
        __syncthreads();
    }
    if (i < n) rs[i] = tmp[threadIdx.x];
    if (threadIdx.x == SCAN_BLK - 1) partials[blockIdx.x] = tmp[SCAN_BLK - 1];
}

__global__ void scan_phase2(int* __restrict__ partials, int nb) {
    if (blockIdx.x == 0 && threadIdx.x == 0) {
        int s = 0;
        for (int i = 0; i < nb; i++) { s += partials[i]; partials[i] = s; }
    }
}

__global__ __launch_bounds__(SCAN_BLK) void scan_phase3(const int* __restrict__ deg,
                                                        int* __restrict__ rs,
                                                        const int* __restrict__ partials,
                                                        int n) {
    int i = blockIdx.x * SCAN_BLK + threadIdx.x;
    if (i < n) {
        int off = (blockIdx.x > 0) ? partials[blockIdx.x - 1] : 0;
        rs[i] = rs[i] + off - deg[i];
    } else if (i == n) {
        rs[n] = partials[gridDim.x - 1];
    }
}

__global__ __launch_bounds__(256) void fill_kernel(const int* __restrict__ ei,
                                                   int* __restrict__ cursor,
                                                   int* __restrict__ csr_src) {
    int e = blockIdx.x * 256 + threadIdx.x;
    if (e >= ETOT) return;
    int s, d;
    if (e < E_EDGES) { s = ei[e]; d = ei[E_EDGES + e]; }
    else             { s = d = e - E_EDGES; }
    int pos = atomicAdd(&cursor[d], 1);
    csr_src[pos] = s;
}

// ---------------- CSR gather-aggregate (bf16 in/out), fused softmax+bias+relu ----------------
// ONE WAVE per dst node (4 nodes / 256-thr block); lane owns 4 channels (8B loads).
// Numerics identical to previous version (same per-channel sequential sum over p).
__global__ __launch_bounds__(256) void agg_kernel(const int* __restrict__ rs,
                                                  const int* __restrict__ csr_src,
                                                  const __hip_bfloat16* __restrict__ xh,
                                                  const float* __restrict__ as_,
                                                  const float* __restrict__ ad_,
                                                  const float* __restrict__ bias,
                                                  __hip_bfloat16* __restrict__ out) {
    int wid = threadIdx.x >> 6;
    int n = blockIdx.x * 4 + wid;
    if (n >= N_NODES) return;
    int lane = threadIdx.x & 63;
    int h = lane >> 4;            // 16 lanes per head
    int cq = lane;                // uint2 index: channels 4*lane .. 4*lane+3
    int beg = rs[n], end = rs[n + 1];
    float adv = ad_[n * HEADS + h];
    float acc0 = 0.f, acc1 = 0.f, acc2 = 0.f, acc3 = 0.f, wsum = 0.f;
    const uint2* xh4 = (const uint2*)xh;   // 8B = 4 bf16
#pragma unroll 4
    for (int p = beg; p < end; ++p) {
        int s = csr_src[p];
        float l = as_[s * HEADS + h] + adv;
        l = l > 0.f ? l : NEG_SLOPE * l;
        float wv = __expf(l);
        wsum += wv;
        uint2 v = xh4[(long)s * (HC / 4) + cq];
        float f0 = __uint_as_float(v.x << 16);
        float f1 = __uint_as_float(v.x & 0xffff0000u);
        float f2 = __uint_as_float(v.y << 16);
        float f3 = __uint_as_float(v.y & 0xffff0000u);
        acc0 += wv * f0;
        acc1 += wv * f1;
        acc2 += wv * f2;
        acc3 += wv * f3;
    }
    float inv = 1.f / (wsum + 1e-16f);
    float4 bi = *(const float4*)&bias[4 * lane];
    __hip_bfloat162 p01, p23;
    p01.x = __float2bfloat16(fmaxf(acc0 * inv + bi.x, 0.f));
    p01.y = __float2bfloat16(fmaxf(acc1 * inv + bi.y, 0.f));
    p23.x = __float2bfloat16(fmaxf(acc2 * inv + bi.z, 0.f));
    p23.y = __float2bfloat16(fmaxf(acc3 * inv + bi.w, 0.f));
    uint2 pk;
    pk.x = *(unsigned int*)&p01;
    pk.y = *(unsigned int*)&p23;
    *(uint2*)&out[(long)n * HC + 4 * lane] = pk;
}

extern "C" void kernel_launch(void* const* d_in, const int* in_sizes, int n_in,
                              void* d_out, int out_size, void* d_ws, size_t ws_size,
                              hipStream_t stream) {
    const float* x    = (const float*)d_in[0];
    const int*   ei   = (const int*)d_in[1];
    const float* W1   = (const float*)d_in[3];
    const float* a_s1 = (const float*)d_in[4];
    const float* a_d1 = (const float*)d_in[5];
    const float* b1   = (const float*)d_in[6];
    const float* W2   = (const float*)d_in[7];
    const float* a_s2 = (const float*)d_in[8];
    const float* a_d2 = (const float*)d_in[9];
    const float* b2   = (const float*)d_in[10];
    const float* Wfc  = (const float*)d_in[11];
    const float* bfc  = (const float*)d_in[12];
    float* out = (float*)d_out;

    char* ws = (char*)d_ws;
    size_t off = 0;
    __hip_bfloat16* xb  = (__hip_bfloat16*)(ws + off); off += (size_t)N_NODES * IN_DIM * 2;  // 12.8MB
    __hip_bfloat16* xh  = (__hip_bfloat16*)(ws + off); off += (size_t)N_NODES * HC * 2;      // 25.6MB
    __hip_bfloat16* y   = (__hip_bfloat16*)(ws + off); off += (size_t)N_NODES * HC * 2;      // 25.6MB
    __hip_bfloat16* W1t = (__hip_bfloat16*)(ws + off); off += (size_t)HC * IN_DIM * 2;
    __hip_bfloat16* W2t = (__hip_bfloat16*)(ws + off); off += (size_t)HC * HC * 2;
    __hip_bfloat16* Wft = (__hip_bfloat16*)(ws + off); off += (size_t)OUT_DIM * HC * 2;
    float* asb     = (float*)(ws + off); off += (size_t)N_NODES * HEADS * 4;
    float* adb     = (float*)(ws + off); off += (size_t)N_NODES * HEADS * 4;
    int*   deg     = (int*)(ws + off);   off += (size_t)N_NODES * 4;
    int*   rs      = (int*)(ws + off);   off += (size_t)(N_NODES + 1) * 4;
    int*   cursor  = (int*)(ws + off);   off += (size_t)N_NODES * 4;
    int*   partials= (int*)(ws + off);   off += 256 * 4;
    int*   csr_src = (int*)(ws + off);   off += (size_t)ETOT * 4;

    int mblocks = (N_NODES + 63) / 64;
    int edge_blocks  = (ETOT + 255) / 256;
    int scan_blocks  = (N_NODES + SCAN_BLK - 1) / SCAN_BLK;
    int scan_blocks3 = (N_NODES + 1 + SCAN_BLK - 1) / SCAN_BLK;
    int agg_blocks   = (N_NODES + 3) / 4;

    // ---------- converts ----------
    long x4 = (long)N_NODES * IN_DIM / 4;
    cvt_bf16<<<(int)((x4 + 255) / 256), 256, 0, stream>>>(x, xb, x4);
    wtrans<<<(IN_DIM * HC + 255) / 256, 256, 0, stream>>>(W1, W1t, IN_DIM, HC);
    wtrans<<<(HC * HC + 255) / 256, 256, 0, stream>>>(W2, W2t, HC, HC);
    wtrans<<<(HC * OUT_DIM + 255) / 256, 256, 0, stream>>>(Wfc, Wft, HC, OUT_DIM);

    // ---------- CSR build (shared by both layers) ----------
    hipMemsetAsync(deg, 0, (size_t)N_NODES * 4, stream);
    hist_kernel<<<edge_blocks, 256, 0, stream>>>(ei, deg);
    scan_phase1<<<scan_blocks, SCAN_BLK, 0, stream>>>(deg, rs, partials, N_NODES);
    scan_phase2<<<1, 64, 0, stream>>>(partials, scan_blocks);
    scan_phase3<<<scan_blocks3, SCAN_BLK, 0, stream>>>(deg, rs, partials, N_NODES);
    hipMemcpyAsync(cursor, rs, (size_t)N_NODES * 4, hipMemcpyDeviceToDevice, stream);
    fill_kernel<<<edge_blocks, 256, 0, stream>>>(ei, cursor, csr_src);

    // ---------- layer 1 ----------
    gemm_xh_mfma<IN_DIM><<<mblocks, 256, 0, stream>>>(xb, W1t, xh, N_NODES, a_s1, a_d1, asb, adb);
    agg_kernel<<<agg_blocks, 256, 0, stream>>>(rs, csr_src, xh, asb, adb, b1, y);

    // ---------- layer 2 ----------
    gemm_xh_mfma<HC><<<mblocks, 256, 0, stream>>>(y, W2t, xh, N_NODES, a_s2, a_d2, asb, adb);
    agg_kernel<<<agg_blocks, 256, 0, stream>>>(rs, csr_src, xh, asb, adb, b2, y);

    // ---------- fc head ----------
    gemm_fc_mfma<<<mblocks, 256, 0, stream>>>(y, Wft, bfc, out, N_NODES);
}

// Round 7
// 421.490 us; speedup vs baseline: 1.0449x; 1.0449x over previous
//
#include <hip/hip_runtime.h>
#include <hip/hip_bf16.h>

#define N_NODES 50000
#define E_EDGES 800000
#define ETOT (E_EDGES + N_NODES)   // self-loops appended
#define IN_DIM 128
#define HID 64
#define HEADS 4
#define HC (HEADS * HID)           // 256
#define OUT_DIM 64
#define NEG_SLOPE 0.2f
#define SCAN_BLK 1024

using bf16x8 = __attribute__((ext_vector_type(8))) __bf16;
using f32x4  = __attribute__((ext_vector_type(4))) float;

// ---------------- fp32 -> bf16 convert (x) ----------------
__global__ __launch_bounds__(256) void cvt_bf16(const float* __restrict__ in,
                                                __hip_bfloat16* __restrict__ out,
                                                long n4) {   // n4 = n/4
    long i = (long)blockIdx.x * 256 + threadIdx.x;
    if (i >= n4) return;
    float4 v = ((const float4*)in)[i];
    __hip_bfloat162 a, b;
    a.x = __float2bfloat16(v.x); a.y = __float2bfloat16(v.y);
    b.x = __float2bfloat16(v.z); b.y = __float2bfloat16(v.w);
    ((__hip_bfloat162*)out)[2 * i]     = a;
    ((__hip_bfloat162*)out)[2 * i + 1] = b;
}

// ---------------- all three weights: W[K][N] fp32 -> Wt[N][K] bf16, one kernel ----------------
__global__ __launch_bounds__(256) void prep_weights(const float* __restrict__ W1,
                                                    const float* __restrict__ W2,
                                                    const float* __restrict__ Wfc,
                                                    __hip_bfloat16* __restrict__ W1t,
                                                    __hip_bfloat16* __restrict__ W2t,
                                                    __hip_bfloat16* __restrict__ Wft) {
    int i = blockIdx.x * 256 + threadIdx.x;
    if (i < 32768) {                       // W1: [128][256]
        int k = i >> 8, n = i & 255;
        W1t[n * IN_DIM + k] = __float2bfloat16(W1[i]);
    } else if (i < 98304) {                // W2: [256][256]
        int j = i - 32768;
        int k = j >> 8, n = j & 255;
        W2t[n * HC + k] = __float2bfloat16(W2[j]);
    } else if (i < 114688) {               // Wfc: [256][64]
        int j = i - 98304;
        int k = j >> 6, n = j & 63;
        Wft[n * HC + k] = __float2bfloat16(Wfc[j]);
    }
}

// ---------------- MFMA GEMM + fused alphas ----------------
// C[M][256] = A[M][K](bf16) @ Bt[256][K](bf16). 256 thr = 4 waves; wave h = head h.
// C written back through LDS for coalesced uint4 stores.
template <int K>
__global__ __launch_bounds__(256) void gemm_xh_mfma(const __hip_bfloat16* __restrict__ A,
                                                    const __hip_bfloat16* __restrict__ Bt,
                                                    __hip_bfloat16* __restrict__ Cb,
                                                    int M,
                                                    const float* __restrict__ a_src,
                                                    const float* __restrict__ a_dst,
                                                    float* __restrict__ as_,
                                                    float* __restrict__ ad_) {
    constexpr int LDSA = 64 * (K + 8) * 2;
    constexpr int LDSC = 64 * HC * 2;          // 32768
    constexpr int SMEM = LDSA > LDSC ? LDSA : LDSC;
    __shared__ char smem[SMEM];
    unsigned short (*Atile)[K + 8] = (unsigned short (*)[K + 8])smem;

    const int t = threadIdx.x;
    const int h = t >> 6;          // wave = head
    const int lane = t & 63;
    const int l15 = lane & 15, l4 = lane >> 4;
    const int m0 = blockIdx.x * 64;

    // ---- stage A tile (64 x K bf16), reg->LDS, +8 pad => 2-way-free ds_read ----
    constexpr int KB8 = K / 8;
#pragma unroll
    for (int i = 0; i < K / 32; i++) {
        int q = i * 256 + t;
        int row = q / KB8;
        int kc = (q - row * KB8) * 8;
        int gm = m0 + row;
        uint4 v = make_uint4(0, 0, 0, 0);
        if (gm < M) v = *(const uint4*)(A + (long)gm * K + kc);
        *(uint4*)&Atile[row][kc] = v;
    }
    __syncthreads();

    f32x4 acc[4][4];
#pragma unroll
    for (int i = 0; i < 4; i++)
#pragma unroll
        for (int j = 0; j < 4; j++) acc[i][j] = (f32x4)0.f;

    const __hip_bfloat16* Bp = Bt + ((long)(h * 64 + l15)) * K + l4 * 8;
    constexpr int NK = K / 32;
    bf16x8 bcur[4], bnxt[4];
#pragma unroll
    for (int cb = 0; cb < 4; cb++) bcur[cb] = *(const bf16x8*)(Bp + (long)cb * 16 * K);

#pragma unroll
    for (int kb = 0; kb < NK; kb++) {
        if (kb + 1 < NK) {
#pragma unroll
            for (int cb = 0; cb < 4; cb++)
                bnxt[cb] = *(const bf16x8*)(Bp + (long)cb * 16 * K + (kb + 1) * 32);
        }
        bf16x8 afr[4];
#pragma unroll
        for (int rb = 0; rb < 4; rb++)
            afr[rb] = *(const bf16x8*)&Atile[rb * 16 + l15][kb * 32 + l4 * 8];
#pragma unroll
        for (int rb = 0; rb < 4; rb++)
#pragma unroll
            for (int cb = 0; cb < 4; cb++)
                acc[rb][cb] = __builtin_amdgcn_mfma_f32_16x16x32_bf16(afr[rb], bcur[cb], acc[rb][cb], 0, 0, 0);
#pragma unroll
        for (int cb = 0; cb < 4; cb++) bcur[cb] = bnxt[cb];
    }

    // ---- alphas from fp32 accumulators (register-only + shfl) ----
    float asv[4], adv[4];
#pragma unroll
    for (int cb = 0; cb < 4; cb++) {
        asv[cb] = a_src[h * HID + cb * 16 + l15];
        adv[cb] = a_dst[h * HID + cb * 16 + l15];
    }
#pragma unroll
    for (int rb = 0; rb < 4; rb++) {
#pragma unroll
        for (int reg = 0; reg < 4; reg++) {
            int row = m0 + rb * 16 + l4 * 4 + reg;
            float ps = 0.f, pd = 0.f;
#pragma unroll
            for (int cb = 0; cb < 4; cb++) {
                ps += acc[rb][cb][reg] * asv[cb];
                pd += acc[rb][cb][reg] * adv[cb];
            }
#pragma unroll
            for (int off = 8; off; off >>= 1) {
                ps += __shfl_down(ps, off);
                pd += __shfl_down(pd, off);
            }
            if (l15 == 0 && row < M) {
                as_[row * HEADS + h] = ps;
                ad_[row * HEADS + h] = pd;
            }
        }
    }

    // ---- C writeback: acc -> LDS (bf16) -> coalesced uint4 global stores ----
    __syncthreads();   // done reading Atile
    unsigned short* Ct = (unsigned short*)smem;   // [64][256]
#pragma unroll
    for (int rb = 0; rb < 4; rb++) {
#pragma unroll
        for (int cb = 0; cb < 4; cb++) {
#pragma unroll
            for (int reg = 0; reg < 4; reg++) {
                int rl = rb * 16 + l4 * 4 + reg;
                int col = h * 64 + cb * 16 + l15;
                __hip_bfloat16 bv = __float2bfloat16(acc[rb][cb][reg]);
                Ct[rl * HC + col] = *(unsigned short*)&bv;
            }
        }
    }
    __syncthreads();
#pragma unroll
    for (int i = 0; i < 8; i++) {            // 64 rows * 512B = 2048 x 16B chunks
        int idx = i * 256 + t;
        int row = idx >> 5;
        int cc  = idx & 31;
        int gm = m0 + row;
        if (gm < M)
            *(uint4*)&Cb[(long)gm * HC + cc * 8] = *(const uint4*)&Ct[row * HC + cc * 8];
    }
}

// ---------------- MFMA FC: out[M][64] = A[M][256](bf16) @ Wfct + bias ----------------
__global__ __launch_bounds__(256) void gemm_fc_mfma(const __hip_bfloat16* __restrict__ A,
                                                    const __hip_bfloat16* __restrict__ Bt,  // [64][256]
                                                    const float* __restrict__ bias,
                                                    float* __restrict__ C,
                                                    int M) {
    constexpr int K = 256;
    constexpr int LDSA = 64 * (K + 8) * 2;     // 33792 > 16384 C-tile
    __shared__ char smem[LDSA];
    unsigned short (*Atile)[K + 8] = (unsigned short (*)[K + 8])smem;

    const int t = threadIdx.x;
    const int w = t >> 6;
    const int lane = t & 63;
    const int l15 = lane & 15, l4 = lane >> 4;
    const int m0 = blockIdx.x * 64;

    constexpr int KB8 = K / 8;
#pragma unroll
    for (int i = 0; i < K / 32; i++) {
        int q = i * 256 + t;
        int row = q / KB8;
        int kc = (q - row * KB8) * 8;
        int gm = m0 + row;
        uint4 v = make_uint4(0, 0, 0, 0);
        if (gm < M) v = *(const uint4*)(A + (long)gm * K + kc);
        *(uint4*)&Atile[row][kc] = v;
    }
    __syncthreads();

    f32x4 acc[4];
#pragma unroll
    for (int j = 0; j < 4; j++) acc[j] = (f32x4)0.f;

    const __hip_bfloat16* Bp = Bt + (long)l15 * K + l4 * 8;
#pragma unroll
    for (int kb = 0; kb < K / 32; kb++) {
        bf16x8 afr = *(const bf16x8*)&Atile[w * 16 + l15][kb * 32 + l4 * 8];
#pragma unroll
        for (int cb = 0; cb < 4; cb++) {
            bf16x8 bfr = *(const bf16x8*)(Bp + (long)cb * 16 * K + kb * 32);
            acc[cb] = __builtin_amdgcn_mfma_f32_16x16x32_bf16(afr, bfr, acc[cb], 0, 0, 0);
        }
    }

    // C -> LDS (fp32, +bias) -> coalesced uint4 stores
    __syncthreads();
    float* Ct = (float*)smem;                  // [64][64]
#pragma unroll
    for (int cb = 0; cb < 4; cb++) {
        int col = cb * 16 + l15;
        float bv = bias[col];
#pragma unroll
        for (int reg = 0; reg < 4; reg++) {
            int rl = w * 16 + l4 * 4 + reg;
            Ct[rl * OUT_DIM + col] = acc[cb][reg] + bv;
        }
    }
    __syncthreads();
#pragma unroll
    for (int i = 0; i < 4; i++) {              // 64 rows * 256B = 1024 x 16B chunks
        int idx = i * 256 + t;
        int row = idx >> 4;
        int cc  = idx & 15;
        int gm = m0 + row;
        if (gm < M)
            *(uint4*)&C[(long)gm * OUT_DIM + cc * 4] = *(const uint4*)&Ct[row * OUT_DIM + cc * 4];
    }
}

// ---------------- CSR build ----------------
__global__ __launch_bounds__(256) void hist_kernel(const int* __restrict__ ei,
                                                   int* __restrict__ deg) {
    int e = blockIdx.x * 256 + threadIdx.x;
    if (e >= ETOT) return;
    int d = (e < E_EDGES) ? ei[E_EDGES + e] : e - E_EDGES;
    atomicAdd(&deg[d], 1);
}

__global__ __launch_bounds__(SCAN_BLK) void scan_phase1(const int* __restrict__ deg,
                                                        int* __restrict__ rs,
                                                        int* __restrict__ partials,
                                                        int n) {
    __shared__ int tmp[SCAN_BLK];
    int i = blockIdx.x * SCAN_BLK + threadIdx.x;
    int v = (i < n) ? deg[i] : 0;
    tmp[threadIdx.x] = v;
    __syncthreads();
    for (int off = 1; off < SCAN_BLK; off <<= 1) {
        int t = (threadIdx.x >= (unsigned)off) ? tmp[threadIdx.x - off] : 0;
        __syncthreads();
        tmp[threadIdx.x] += t;
        __syncthreads();
    }
    if (i < n) rs[i] = tmp[threadIdx.x];
    if (threadIdx.x == SCAN_BLK - 1) partials[blockIdx.x] = tmp[SCAN_BLK - 1];
}

// global exclusive fixup; scans the <=64 block partials in-wave (no serial kernel),
// writes rs[i] AND cursor[i] (drops the d2d memcpy).
__global__ __launch_bounds__(SCAN_BLK) void scan_phase3(const int* __restrict__ deg,
                                                        int* __restrict__ rs,
                                                        int* __restrict__ cursor,
                                                        const int* __restrict__ partials,
                                                        int nb, int n) {
    __shared__ int sOff[2];
    if (threadIdx.x < 64) {
        int lane = threadIdx.x;
        int v = (lane < nb) ? partials[lane] : 0;
#pragma unroll
        for (int off = 1; off < 64; off <<= 1) {
            int tv = __shfl_up(v, off);
            if (lane >= off) v += tv;
        }
        if ((int)blockIdx.x > 0 && lane == (int)blockIdx.x - 1) sOff[0] = v;
        if (lane == nb - 1) sOff[1] = v;
        if (blockIdx.x == 0 && lane == 0) sOff[0] = 0;
    }
    __syncthreads();
    int i = blockIdx.x * SCAN_BLK + threadIdx.x;
    if (i < n) {
        int e = rs[i] + sOff[0] - deg[i];
        rs[i] = e;
        cursor[i] = e;
    } else if (i == n) {
        rs[n] = sOff[1];
    }
}

__global__ __launch_bounds__(256) void fill_kernel(const int* __restrict__ ei,
                                                   int* __restrict__ cursor,
                                                   int* __restrict__ csr_src) {
    int e = blockIdx.x * 256 + threadIdx.x;
    if (e >= ETOT) return;
    int s, d;
    if (e < E_EDGES) { s = ei[e]; d = ei[E_EDGES + e]; }
    else             { s = d = e - E_EDGES; }
    int pos = atomicAdd(&cursor[d], 1);
    csr_src[pos] = s;
}

// ---------------- CSR gather-aggregate (bf16 in/out), fused softmax+bias+relu ----------------
// ONE WAVE per dst node; lane owns 4 channels (8B loads). (Latency-bound; r6-verified.)
__global__ __launch_bounds__(256) void agg_kernel(const int* __restrict__ rs,
                                                  const int* __restrict__ csr_src,
                                                  const __hip_bfloat16* __restrict__ xh,
                                                  const float* __restrict__ as_,
                                                  const float* __restrict__ ad_,
                                                  const float* __restrict__ bias,
                                                  __hip_bfloat16* __restrict__ out) {
    int wid = threadIdx.x >> 6;
    int n = blockIdx.x * 4 + wid;
    if (n >= N_NODES) return;
    int lane = threadIdx.x & 63;
    int h = lane >> 4;
    int cq = lane;
    int beg = rs[n], end = rs[n + 1];
    float adv = ad_[n * HEADS + h];
    float acc0 = 0.f, acc1 = 0.f, acc2 = 0.f, acc3 = 0.f, wsum = 0.f;
    const uint2* xh4 = (const uint2*)xh;
#pragma unroll 4
    for (int p = beg; p < end; ++p) {
        int s = csr_src[p];
        float l = as_[s * HEADS + h] + adv;
        l = l > 0.f ? l : NEG_SLOPE * l;
        float wv = __expf(l);
        wsum += wv;
        uint2 v = xh4[(long)s * (HC / 4) + cq];
        float f0 = __uint_as_float(v.x << 16);
        float f1 = __uint_as_float(v.x & 0xffff0000u);
        float f2 = __uint_as_float(v.y << 16);
        float f3 = __uint_as_float(v.y & 0xffff0000u);
        acc0 += wv * f0;
        acc1 += wv * f1;
        acc2 += wv * f2;
        acc3 += wv * f3;
    }
    float inv = 1.f / (wsum + 1e-16f);
    float4 bi = *(const float4*)&bias[4 * lane];
    __hip_bfloat162 p01, p23;
    p01.x = __float2bfloat16(fmaxf(acc0 * inv + bi.x, 0.f));
    p01.y = __float2bfloat16(fmaxf(acc1 * inv + bi.y, 0.f));
    p23.x = __float2bfloat16(fmaxf(acc2 * inv + bi.z, 0.f));
    p23.y = __float2bfloat16(fmaxf(acc3 * inv + bi.w, 0.f));
    uint2 pk;
    pk.x = *(unsigned int*)&p01;
    pk.y = *(unsigned int*)&p23;
    *(uint2*)&out[(long)n * HC + 4 * lane] = pk;
}

extern "C" void kernel_launch(void* const* d_in, const int* in_sizes, int n_in,
                              void* d_out, int out_size, void* d_ws, size_t ws_size,
                              hipStream_t stream) {
    const float* x    = (const float*)d_in[0];
    const int*   ei   = (const int*)d_in[1];
    const float* W1   = (const float*)d_in[3];
    const float* a_s1 = (const float*)d_in[4];
    const float* a_d1 = (const float*)d_in[5];
    const float* b1   = (const float*)d_in[6];
    const float* W2   = (const float*)d_in[7];
    const float* a_s2 = (const float*)d_in[8];
    const float* a_d2 = (const float*)d_in[9];
    const float* b2   = (const float*)d_in[10];
    const float* Wfc  = (const float*)d_in[11];
    const float* bfc  = (const float*)d_in[12];
    float* out = (float*)d_out;

    char* ws = (char*)d_ws;
    size_t off = 0;
    __hip_bfloat16* xb  = (__hip_bfloat16*)(ws + off); off += (size_t)N_NODES * IN_DIM * 2;
    __hip_bfloat16* xh  = (__hip_bfloat16*)(ws + off); off += (size_t)N_NODES * HC * 2;
    __hip_bfloat16* y   = (__hip_bfloat16*)(ws + off); off += (size_t)N_NODES * HC * 2;
    __hip_bfloat16* W1t = (__hip_bfloat16*)(ws + off); off += (size_t)HC * IN_DIM * 2;
    __hip_bfloat16* W2t = (__hip_bfloat16*)(ws + off); off += (size_t)HC * HC * 2;
    __hip_bfloat16* Wft = (__hip_bfloat16*)(ws + off); off += (size_t)OUT_DIM * HC * 2;
    float* asb     = (float*)(ws + off); off += (size_t)N_NODES * HEADS * 4;
    float* adb     = (float*)(ws + off); off += (size_t)N_NODES * HEADS * 4;
    int*   deg     = (int*)(ws + off);   off += (size_t)N_NODES * 4;
    int*   rs      = (int*)(ws + off);   off += (size_t)(N_NODES + 1) * 4;
    int*   cursor  = (int*)(ws + off);   off += (size_t)N_NODES * 4;
    int*   partials= (int*)(ws + off);   off += 256 * 4;
    int*   csr_src = (int*)(ws + off);   off += (size_t)ETOT * 4;

    int mblocks = (N_NODES + 63) / 64;
    int edge_blocks  = (ETOT + 255) / 256;
    int scan_blocks  = (N_NODES + SCAN_BLK - 1) / SCAN_BLK;
    int scan_blocks3 = (N_NODES + 1 + SCAN_BLK - 1) / SCAN_BLK;
    int agg_blocks   = (N_NODES + 3) / 4;

    // ---------- converts ----------
    long x4 = (long)N_NODES * IN_DIM / 4;
    cvt_bf16<<<(int)((x4 + 255) / 256), 256, 0, stream>>>(x, xb, x4);
    prep_weights<<<(114688 + 255) / 256, 256, 0, stream>>>(W1, W2, Wfc, W1t, W2t, Wft);

    // ---------- CSR build (shared by both layers) ----------
    hipMemsetAsync(deg, 0, (size_t)N_NODES * 4, stream);
    hist_kernel<<<edge_blocks, 256, 0, stream>>>(ei, deg);
    scan_phase1<<<scan_blocks, SCAN_BLK, 0, stream>>>(deg, rs, partials, N_NODES);
    scan_phase3<<<scan_blocks3, SCAN_BLK, 0, stream>>>(deg, rs, cursor, partials, scan_blocks, N_NODES);
    fill_kernel<<<edge_blocks, 256, 0, stream>>>(ei, cursor, csr_src);

    // ---------- layer 1 ----------
    gemm_xh_mfma<IN_DIM><<<mblocks, 256, 0, stream>>>(xb, W1t, xh, N_NODES, a_s1, a_d1, asb, adb);
    agg_kernel<<<agg_blocks, 256, 0, stream>>>(rs, csr_src, xh, asb, adb, b1, y);

    // ---------- layer 2 ----------
    gemm_xh_mfma<HC><<<mblocks, 256, 0, stream>>>(y, W2t, xh, N_NODES, a_s2, a_d2, asb, adb);
    agg_kernel<<<agg_blocks, 256, 0, stream>>>(rs, csr_src, xh, asb, adb, b2, y);

    // ---------- fc head ----------
    gemm_fc_mfma<<<mblocks, 256, 0, stream>>>(y, Wft, bfc, out, N_NODES);
}